// Round 6
// baseline (254.229 us; speedup 1.0000x reference)
//
#include <hip/hip_runtime.h>

#define SEQ 512
#define NB  512
#define NT  96

typedef float f2 __attribute__((ext_vector_type(2)));

// One block = one batch chain, 96 threads (thread j owns tag-column j).
// Linear-domain forward recursion (A = exp(alpha) * 2^K):
//   A'[j] = (sum_k A[k]*E[k][j]) * exp(em[i][j]) * 2^-ki
// E-table packed along K (f2 colp[48] = 96 VGPRs), inner loop = 48
// v_pk_fma_f32. No transcendentals on the serial chain.
//
// KEY (R6): the in-loop barrier is raw `s_waitcnt lgkmcnt(0); s_barrier`
// -- NOT __syncthreads(), whose implicit vmcnt(0) drain exposed a full
// HBM round-trip per step (the dominant cost in R1/R3/R5). Emission
// prefetch loads now stay in flight across barriers (counted-vmcnt
// inserted automatically at emq1's use, 3 steps later).
__launch_bounds__(NT, 1)
__global__ void crf_lin96(const float* __restrict__ logits,
                          const int*   __restrict__ tags,
                          const int*   __restrict__ mask,
                          const float* __restrict__ trans,
                          const float* __restrict__ startt,
                          const float* __restrict__ endt,
                          float* __restrict__ out)
{
    const int b = blockIdx.x;
    const int j = threadIdx.x;              // 0..95
    const float* em = logits + (size_t)b * SEQ * NT;

    __shared__ __align__(16) float Abuf[4][NT];
    __shared__ float red[NT];
    __shared__ float num_red[NT];
    __shared__ int tg_s[SEQ];
    __shared__ int mk_s[SEQ];

    for (int i = j; i < SEQ; i += NT) {
        tg_s[i] = tags[(size_t)b * SEQ + i];
        mk_s[i] = mask[(size_t)b * SEQ + i];
    }

    // E-table column j, K-packed: colp[m] = (exp(T[2m][j]), exp(T[2m+1][j]))
    f2 colp[48];
#pragma unroll
    for (int m = 0; m < 48; ++m) {
        colp[m].x = __expf(trans[(2 * m + 0) * NT + j]);
        colp[m].y = __expf(trans[(2 * m + 1) * NT + j]);
    }

    float A = __expf(startt[j] + em[j]);    // A0 = exp(start + em[0]), K = 0
    int K = 0;
    Abuf[0][j] = A;

    float emq1 = em[1 * NT + j];
    float emq2 = em[2 * NT + j];
    float emq3 = em[3 * NT + j];
    __syncthreads();                        // once (full drain OK here)

    for (int i = 1; i < SEQ; ++i) {
        // issue next emission prefetch FIRST (stays in flight across barriers)
        float emn = 0.f;
        if (i + 3 < SEQ) emn = em[(i + 3) * NT + j];
        const float w = __expf(emq1);       // overlaps ds_read latency
        const int mk = mk_s[i];

        const float4* e4 = (const float4*)Abuf[(i - 1) & 3];
        f2 acc[8];
#pragma unroll
        for (int m = 0; m < 8; ++m) { acc[m].x = 0.f; acc[m].y = 0.f; }
        float A0prev = 0.f;
#pragma unroll
        for (int q = 0; q < 24; ++q) {
            const float4 ev = e4[q];        // broadcast b128, conflict-free
            if (q == 0) A0prev = ev.x;
            f2 lo; lo.x = ev.x; lo.y = ev.y;
            f2 hi; hi.x = ev.z; hi.y = ev.w;
            acc[(2 * q + 0) & 7] += lo * colp[2 * q + 0];   // v_pk_fma_f32
            acc[(2 * q + 1) & 7] += hi * colp[2 * q + 1];
        }
        const f2 t = ((acc[0] + acc[1]) + (acc[2] + acc[3]))
                   + ((acc[4] + acc[5]) + (acc[6] + acc[7]));
        const float v = t.x + t.y;

        // exact power-of-2 rescale from exponent of A_prev[0] (uniform)
        const unsigned eb = __float_as_uint(A0prev);
        const int expo = (int)((eb >> 23) & 0xFFu);
        const float s = __uint_as_float((unsigned)(247 - expo) << 23); // 2^(120-expo)
        const int ki = expo - 120;

        const float An = v * (w * s);
        if (mk) { A = An; K += ki; }
        Abuf[i & 3][j] = A;
        emq1 = emq2; emq2 = emq3; emq3 = emn;

        // LDS-only barrier: drain lgkm (my ds_write visible), keep vmem
        // prefetches in flight. "memory" clobber pins ds ops on both sides.
        asm volatile("s_waitcnt lgkmcnt(0)\n\ts_barrier" ::: "memory");
    }

    // ---- denominator: log(sum_j A[j]*exp(end[j])) + K*ln2 ----
    red[j] = A * __expf(endt[j]);

    // ---- numerator partials ----
    float pn = 0.f;
    for (int i = 1 + j; i < SEQ; i += NT) {
        if (mk_s[i]) {
            const int tp = tg_s[i - 1], tc = tg_s[i];
            pn += trans[tp * NT + tc] + em[i * NT + tc];
        }
    }
    num_red[j] = pn;
    __syncthreads();

    if (j == 0) {
        float pd = 0.f;
        for (int k = 0; k < NT; ++k) pd += red[k];
        const float denom = __logf(pd) + (float)K * 0.69314718055994531f;

        float num = startt[tg_s[0]] + em[tg_s[0]];
        for (int k = 0; k < NT; ++k) num += num_red[k];
        int cnt = 0;
        for (int i = 0; i < SEQ; ++i) cnt += mk_s[i];
        num += endt[tg_s[cnt - 1]];

        atomicAdd(out, num - denom);
    }
}

extern "C" void kernel_launch(void* const* d_in, const int* in_sizes, int n_in,
                              void* d_out, int out_size, void* d_ws, size_t ws_size,
                              hipStream_t stream)
{
    const float* logits = (const float*)d_in[0];
    const int*   tags   = (const int*)  d_in[1];
    const int*   mask   = (const int*)  d_in[2];
    const float* trans  = (const float*)d_in[3];
    const float* startt = (const float*)d_in[4];
    const float* endt   = (const float*)d_in[5];
    float* out = (float*)d_out;

    hipMemsetAsync(out, 0, out_size * sizeof(float), stream);
    crf_lin96<<<NB, NT, 0, stream>>>(logits, tags, mask, trans,
                                     startt, endt, out);
}

// Round 7
// 224.392 us; speedup vs baseline: 1.1330x; 1.1330x over previous
//
#include <hip/hip_runtime.h>

#define SEQ 512
#define NBAT 512
#define NT 96
#define G 16
#define NBLK (NBAT / G)   // 32 blocks
#define TPB 384           // 6 waves

typedef float f32x4 __attribute__((ext_vector_type(4)));
typedef short bf16x8 __attribute__((ext_vector_type(8)));
typedef short short4v __attribute__((ext_vector_type(4)));

__device__ __forceinline__ short f2bf(float f) {
    unsigned u = __float_as_uint(f);
    u += 0x7FFFu + ((u >> 16) & 1u);       // round-to-nearest-even
    return (short)(u >> 16);
}
__device__ __forceinline__ float bf2f(short s) {
    return __uint_as_float(((unsigned)(unsigned short)s) << 16);
}

// 16 batches/block, 6 waves. Per step one transposed GEMM via MFMA:
//   S^T[j][g] = sum_k E[k][j] * A^T[k][g]   (wave w: tag rows 16w..16w+15)
// State A^T kept in LDS as bf16 (double-buffered). Per-batch power-of-2
// rescale (lag-1, scl[] LDS row), K_g integer exponent tracked by wave-0
// lanes. No transcendentals on the serial chain; ONE lgkm-only barrier/step.
__launch_bounds__(TPB)
__global__ void crf_mfma(const float* __restrict__ logits,
                         const int*   __restrict__ tags,
                         const int*   __restrict__ mask,
                         const float* __restrict__ trans,
                         const float* __restrict__ startt,
                         const float* __restrict__ endt,
                         float* __restrict__ out)
{
    const int bg = blockIdx.x * G;
    const int t = threadIdx.x;
    const int w = t >> 6;          // wave 0..5 -> tag rows 16w..16w+15
    const int l = t & 63;
    const int g = l & 15;          // batch column
    const int q = l >> 4;          // quad 0..3

    __shared__ __align__(16) short AT[2][G][NT];   // bf16 state (6 KiB)
    __shared__ float sclf[2][G];
    __shared__ unsigned mkb[SEQ];
    __shared__ float expend[NT];
    __shared__ float nred[24][G];
    __shared__ float cred[24][G];

    // ---- stage mask bits: mkb[i] bit g = mask[bg+g][i] ----
    for (int i = t; i < SEQ; i += TPB) {
        unsigned v = 0;
        for (int gg = 0; gg < G; ++gg)
            v |= (mask[(size_t)(bg + gg) * SEQ + i] != 0 ? 1u : 0u) << gg;
        mkb[i] = v;
    }
    if (t < NT) expend[t] = __expf(endt[t]);

    // ---- init state: AT[0][g][j] = exp(start[j] + em[g][0][j]) ----
    for (int idx = t; idx < G * NT; idx += TPB) {
        const int gg = idx / NT, j = idx - gg * NT;
        AT[0][gg][j] = f2bf(__expf(startt[j] + logits[(size_t)(bg + gg) * SEQ * NT + j]));
    }

    // ---- E^T fragments (A operand), static in VGPRs ----
    bf16x8 ea0, ea1, ea2;
    {
        const int m = 16 * w + g;  // tag row (output j)
#pragma unroll
        for (int e = 0; e < 8; ++e) {
            ea0[e] = f2bf(__expf(trans[( 0 + q * 8 + e) * NT + m]));
            ea1[e] = f2bf(__expf(trans[(32 + q * 8 + e) * NT + m]));
            ea2[e] = f2bf(__expf(trans[(64 + q * 8 + e) * NT + m]));
        }
    }

    // scl / K bookkeeping (wave 0, lanes 0..15: lane t owns batch t)
    int kcur = 0, K = 0;
    if (t < G) {
        const float ref = __expf(startt[0] + logits[(size_t)(bg + t) * SEQ * NT + 0]);
        kcur = (int)((__float_as_uint(ref) >> 23) & 0xFFu) - 127;
        sclf[0][t] = __uint_as_float((unsigned)(127 - kcur) << 23);  // 2^-kcur
    }

    const int jbase = 16 * w + 4 * q;                  // C rows: 4 consecutive j
    const float* emg = logits + (size_t)(bg + g) * SEQ * NT;

    __syncthreads();

    short4v prev4 = *(const short4v*)&AT[0][g][jbase]; // my state slice

    float4 emq0 = *(const float4*)&emg[1 * NT + jbase];
    float4 emq1 = *(const float4*)&emg[2 * NT + jbase];

    for (int i = 1; i < SEQ; ++i) {
        const int rb = (i - 1) & 1, wb = i & 1;

        float4 emn = make_float4(0.f, 0.f, 0.f, 0.f);
        if (i + 2 < SEQ) emn = *(const float4*)&emg[(i + 2) * NT + jbase];

        const float sc = sclf[rb][g];
        const unsigned mk = (mkb[i] >> g) & 1u;

        bf16x8 b0 = *(const bf16x8*)&AT[rb][g][ 0 + 8 * q];
        bf16x8 b1 = *(const bf16x8*)&AT[rb][g][32 + 8 * q];
        bf16x8 b2 = *(const bf16x8*)&AT[rb][g][64 + 8 * q];

        const float ws0 = __expf(emq0.x) * sc;   // off the MFMA path
        const float ws1 = __expf(emq0.y) * sc;
        const float ws2 = __expf(emq0.z) * sc;
        const float ws3 = __expf(emq0.w) * sc;

        f32x4 acc = {0.f, 0.f, 0.f, 0.f};
        acc = __builtin_amdgcn_mfma_f32_16x16x32_bf16(ea0, b0, acc, 0, 0, 0);
        acc = __builtin_amdgcn_mfma_f32_16x16x32_bf16(ea1, b1, acc, 0, 0, 0);
        acc = __builtin_amdgcn_mfma_f32_16x16x32_bf16(ea2, b2, acc, 0, 0, 0);

        const float a0 = acc[0] * ws0, a1 = acc[1] * ws1;
        const float a2 = acc[2] * ws2, a3 = acc[3] * ws3;
        short4v new4;
        new4[0] = f2bf(a0); new4[1] = f2bf(a1);
        new4[2] = f2bf(a2); new4[3] = f2bf(a3);
        if (mk) prev4 = new4;                       // masked: copy-forward
        *(short4v*)&AT[wb][g][jbase] = prev4;

        if (t < G) {    // lane t: j==0 value is a0 -> next scale + K
            float scn = sc;
            if (mk) {
                K += kcur;
                kcur = (int)((__float_as_uint(a0) >> 23) & 0xFFu) - 127;
                scn = __uint_as_float((unsigned)(127 - kcur) << 23);
            }
            sclf[wb][t] = scn;
        }

        emq0 = emq1; emq1 = emn;
        // lgkm-only barrier: LDS state visible, em prefetches stay in flight
        asm volatile("s_waitcnt lgkmcnt(0)\n\ts_barrier" ::: "memory");
    }

    // ---- numerator partials: t -> (g = t&15, chunk c = t>>4 of 24) ----
    const int c = t >> 4;
    const int gn = t & 15;
    const float* emp = logits + (size_t)(bg + gn) * SEQ * NT;
    const int* tgp = tags + (size_t)(bg + gn) * SEQ;
    float pn = 0.f, pc = 0.f;
    for (int i = 1 + c; i < SEQ; i += 24) {
        if ((mkb[i] >> gn) & 1u) {
            const int tp = tgp[i - 1], tc = tgp[i];
            pn += trans[tp * NT + tc] + emp[i * NT + tc];
        }
    }
    for (int i = c; i < SEQ; i += 24) pc += (float)((mkb[i] >> gn) & 1u);
    nred[c][gn] = pn; cred[c][gn] = pc;
    __syncthreads();

    if (t < G) {
        float num = 0.f; int cnt = 0;
        for (int cc = 0; cc < 24; ++cc) { num += nred[cc][t]; cnt += (int)cred[cc][t]; }
        const int tg0 = tags[(size_t)(bg + t) * SEQ];
        const int tgl = tags[(size_t)(bg + t) * SEQ + cnt - 1];
        num += startt[tg0] + logits[(size_t)(bg + t) * SEQ * NT + tg0] + endt[tgl];

        float sd = 0.f;
        const int fb = (SEQ - 1) & 1;
        for (int j = 0; j < NT; ++j) sd += bf2f(AT[fb][t][j]) * expend[j];
        const float denom = __logf(sd) + (float)K * 0.69314718055994531f;

        float llh = num - denom;
        llh += __shfl_xor(llh, 1);
        llh += __shfl_xor(llh, 2);
        llh += __shfl_xor(llh, 4);
        llh += __shfl_xor(llh, 8);
        if (t == 0) atomicAdd(out, llh);
    }
}

extern "C" void kernel_launch(void* const* d_in, const int* in_sizes, int n_in,
                              void* d_out, int out_size, void* d_ws, size_t ws_size,
                              hipStream_t stream)
{
    const float* logits = (const float*)d_in[0];
    const int*   tags   = (const int*)  d_in[1];
    const int*   mask   = (const int*)  d_in[2];
    const float* trans  = (const float*)d_in[3];
    const float* startt = (const float*)d_in[4];
    const float* endt   = (const float*)d_in[5];
    float* out = (float*)d_out;

    hipMemsetAsync(out, 0, out_size * sizeof(float), stream);
    crf_mfma<<<NBLK, TPB, 0, stream>>>(logits, tags, mask, trans,
                                       startt, endt, out);
}